// Round 5
// baseline (439.054 us; speedup 1.0000x reference)
//
#include <hip/hip_runtime.h>
#include <math.h>

typedef __bf16 bf16;
typedef __bf16 bf16x8 __attribute__((ext_vector_type(8)));
typedef __bf16 bf16x4 __attribute__((ext_vector_type(4)));
typedef float  f32x4  __attribute__((ext_vector_type(4)));

#define HW        16384      // 128*128
#define OUT_ELEMS 4194304    // 4*64*128*128

// padded xm: [b][m][yp=142][xp=142][c=64], pixel (y,x) at (y+7, x+7)
#define XM_ROW    (142 * 64)
#define XM_PLANE  (142 * XM_ROW)          // 1,290,496 el
// padded cat: [b][yp=130][xp=130][ch=256], pixel (y,x) at (y+1, x+1)
#define CAT_ROW   (130 * 256)
#define CAT_PLANE (130 * CAT_ROW)         // 4,326,400 el

// ---------------- weight transforms (fp32 -> bf16, tap-major, c innermost) ----
__global__ void k_wt(const float* __restrict__ kern, const float* __restrict__ w2,
                     bf16* __restrict__ kern_t, bf16* __restrict__ w2_t) {
  int i = blockIdx.x * 256 + threadIdx.x;
  const int N1 = 4 * 3 * 9 * 64 * 64;   // 442368
  if (i < N1) {
    int c = i & 63, o = (i >> 6) & 63, tap = (i >> 12) % 9, bm = i / 36864;
    kern_t[i] = (bf16)kern[(((bm * 64 + o) * 64 + c) * 9) + tap];
  } else {
    int j = i - N1;
    if (j < 64 * 256 * 9) {
      int ch = j & 255, oc = (j >> 8) & 63, tap = j >> 14;
      w2_t[j] = (bf16)w2[(oc * 256 + ch) * 9 + tap];
    }
  }
}

// -------- mask conv stage 1: partial logits over 8-channel groups ------------
__global__ void k_mask1(const float* __restrict__ x, const float* __restrict__ mw,
                        float* __restrict__ part) {
  int y = blockIdx.x, b = blockIdx.y, cg = blockIdx.z;
  int tx = threadIdx.x;      // 0..127
  float a0 = 0.f, a1 = 0.f, a2 = 0.f;
#pragma unroll
  for (int ci = 0; ci < 8; ++ci) {
    int c = cg * 8 + ci;
    const float* xp = x + ((size_t)(b * 64 + c)) * HW;
    const float* w0 = mw + (0 * 64 + c) * 9;
    const float* w1 = mw + (1 * 64 + c) * 9;
    const float* w2 = mw + (2 * 64 + c) * 9;
#pragma unroll
    for (int ky = 0; ky < 3; ++ky) {
      int yy = y + ky - 1;
      if ((unsigned)yy >= 128u) continue;
#pragma unroll
      for (int kx = 0; kx < 3; ++kx) {
        int xx = tx + kx - 1;
        if ((unsigned)xx >= 128u) continue;
        float xv = xp[yy * 128 + xx];
        a0 += xv * w0[ky * 3 + kx];
        a1 += xv * w1[ky * 3 + kx];
        a2 += xv * w2[ky * 3 + kx];
      }
    }
  }
  size_t base = (size_t)((b * 8 + cg) * 3) * HW + y * 128 + tx;
  part[base]          = a0;
  part[base + HW]     = a1;
  part[base + 2 * HW] = a2;
}

// -------- mask conv stage 2: reduce groups + bias + softmax ------------------
__global__ void k_mask2(const float* __restrict__ part, const float* __restrict__ mb,
                        float* __restrict__ masks) {
  int y = blockIdx.x, b = blockIdx.y;
  int tx = threadIdx.x;
  float a0 = mb[0], a1 = mb[1], a2 = mb[2];
  int off = y * 128 + tx;
#pragma unroll
  for (int cg = 0; cg < 8; ++cg) {
    size_t base = (size_t)((b * 8 + cg) * 3) * HW + off;
    a0 += part[base];
    a1 += part[base + HW];
    a2 += part[base + 2 * HW];
  }
  float mx = fmaxf(a0, fmaxf(a1, a2));
  float e0 = __expf(a0 - mx), e1 = __expf(a1 - mx), e2 = __expf(a2 - mx);
  float inv = 1.0f / (e0 + e1 + e2);
  size_t base = ((size_t)b * 3) * HW + off;
  masks[base]          = e0 * inv;
  masks[base + HW]     = e1 * inv;
  masks[base + 2 * HW] = e2 * inv;
}

// -------- xm = x * mask, NCHW fp32 -> padded NHWC(c=64) bf16, incl. halo -----
__global__ void k_xmt(const float* __restrict__ x, const float* __restrict__ masks,
                      bf16* __restrict__ xm_p) {
  int yp = blockIdx.x;  // 0..141 padded row
  int m = blockIdx.y, b = blockIdx.z;
  int t = threadIdx.x;  // 256
  bf16* prow = xm_p + (size_t)(b * 3 + m) * XM_PLANE + (size_t)yp * XM_ROW;
  bf16x8 z = {};
  if (yp < 7 || yp >= 135) {          // full halo row: 142*64/8 = 1136 chunks
#pragma unroll
    for (int i = 0; i < 5; ++i) {
      int u = i * 256 + t;
      if (u < 1136) ((bf16x8*)prow)[u] = z;
    }
    return;
  }
  // side halo: 7 px * 64c = 448 el = 56 chunks each side
  if (t < 56) ((bf16x8*)prow)[t] = z;
  else if (t < 112) ((bf16x8*)(prow + 135 * 64))[t - 56] = z;

  int y = yp - 7;
  __shared__ float tile[64 * 130];
#pragma unroll
  for (int i = 0; i < 32; ++i) {
    int u = i * 256 + t;           // 0..8191
    int c = u >> 7, xx = u & 127;
    tile[c * 130 + xx] = x[((size_t)(b * 64 + c)) * HW + y * 128 + xx];
  }
  __syncthreads();
  const float* mrow = masks + ((size_t)(b * 3 + m)) * HW + y * 128;
  bf16* orow = prow + 7 * 64;
#pragma unroll
  for (int i = 0; i < 32; ++i) {
    int u = i * 256 + t;
    int c = u & 63, xx = u >> 6;
    orow[xx * 64 + c] = (bf16)(tile[c * 130 + xx] * mrow[xx]);
  }
}

// ---------------- zero the halo of cat_p (516 px * 256 ch per plane) ---------
__global__ void k_cat_halo(bf16* __restrict__ cat_p) {
  int id = blockIdx.x * 256 + threadIdx.x;
  if (id >= 4 * 16512) return;
  int plane = id / 16512, j = id % 16512;
  bf16* base = cat_p + (size_t)plane * CAT_PLANE;
  bf16x8 zv = {};
  if (j < 8320) {                         // rows 0 and 129, full 130 px
    int row = (j / 4160) * 129;
    int off = (j % 4160) * 8;
    *(bf16x8*)(base + (size_t)row * CAT_ROW + off) = zv;
  } else {                                // rows 1..128, cols 0 and 129
    int k = j - 8320;
    int row = 1 + (k >> 6);
    int idx = k & 63;
    int col = (idx >> 5) * 129;
    int ch8 = (idx & 31) * 8;
    *(bf16x8*)(base + (size_t)row * CAT_ROW + col * 256 + ch8) = zv;
  }
}

// ------- branch convs: 4x4 wave tile, XCD-swizzled blocks --------------------
// blockIdx.x (0..2047): xcd = bid&7 -> b = xcd>>1, di_hi = xcd&1;
// i = bid>>3 -> di = di_hi*2 + (i&1), y = i>>1.  Each XCD sweeps one b plane
// in y-order => per-XCD L2 working set ~1 MB (xm rows + kern_t[b]).
__global__ __launch_bounds__(128, 3) void k_branch(const bf16* __restrict__ xm_p,
                                                   const bf16* __restrict__ kern_t,
                                                   bf16* __restrict__ cat_p) {
  int bid = blockIdx.x;
  int xcd = bid & 7;
  int i   = bid >> 3;
  int b   = xcd >> 1;
  int di  = ((xcd & 1) << 1) | (i & 1);
  int y   = i >> 1;
  int d  = 1 + 2 * di;           // 1,3,5,7
  int lane = threadIdx.x & 63;
  int wave = threadIdx.x >> 6;   // 0..1
  int lanelo = lane & 15;
  int quad = lane >> 4;
  int xw = wave * 64;            // wave px base

  const bf16* xbase0 = xm_p + (size_t)(7 + d * (-1) + xw + lanelo) * 64 + quad * 8;
  const bf16* wbase0 = kern_t + lanelo * 64 + quad * 8;

  // step s = m*18 + tap*2 + kci  (m 0..2, tap 0..8, kci 0..1)
  auto wptr = [&](int s) {
    int m = s / 18, r = s % 18, tap = r >> 1, kc = (r & 1) * 32;
    return wbase0 + (size_t)((b * 3 + m) * 9 + tap) * 4096 + kc;
  };
  auto bptr = [&](int s) {
    int m = s / 18, r = s % 18, tap = r >> 1, kc = (r & 1) * 32;
    int ky = tap / 3, kx = tap % 3;
    return xbase0 + (size_t)(b * 3 + m) * XM_PLANE
                  + (size_t)(y + 7 + d * (ky - 1)) * XM_ROW
                  + (size_t)(d * kx) * 64 + kc;
  };

  const int NSTEP = 54;
  bf16x8 a[2][4], bv[2][4];
  {
    const bf16* wp = wptr(0);
    const bf16* bp = bptr(0);
#pragma unroll
    for (int mt = 0; mt < 4; ++mt) a[0][mt] = *(const bf16x8*)(wp + mt * 1024);
#pragma unroll
    for (int nt = 0; nt < 4; ++nt) bv[0][nt] = *(const bf16x8*)(bp + nt * 1024);
  }

  f32x4 acc[4][4] = {};
#pragma unroll
  for (int s = 0; s < NSTEP; ++s) {
    int cur = s & 1, nxt = cur ^ 1;
    if (s + 1 < NSTEP) {
      const bf16* wp = wptr(s + 1);
      const bf16* bp = bptr(s + 1);
#pragma unroll
      for (int mt = 0; mt < 4; ++mt) a[nxt][mt] = *(const bf16x8*)(wp + mt * 1024);
#pragma unroll
      for (int nt = 0; nt < 4; ++nt) bv[nxt][nt] = *(const bf16x8*)(bp + nt * 1024);
    }
#pragma unroll
    for (int mt = 0; mt < 4; ++mt)
#pragma unroll
      for (int nt = 0; nt < 4; ++nt)
        acc[mt][nt] = __builtin_amdgcn_mfma_f32_16x16x32_bf16(a[cur][mt], bv[cur][nt], acc[mt][nt], 0, 0, 0);
  }

  // epilogue: cat_p[b][y+1][px+1][di*64+o] bf16
  bf16* cp = cat_p + (size_t)b * CAT_PLANE + (size_t)(y + 1) * CAT_ROW + di * 64;
#pragma unroll
  for (int mt = 0; mt < 4; ++mt) {
#pragma unroll
    for (int nt = 0; nt < 4; ++nt) {
      int o = mt * 16 + quad * 4;
      int px = xw + nt * 16 + lanelo;
      bf16x4 v;
#pragma unroll
      for (int r = 0; r < 4; ++r) v[r] = (bf16)acc[mt][nt][r];
      *(bf16x4*)(cp + (size_t)(px + 1) * 256 + o) = v;
    }
  }
}

// ------- final conv + bias + BN + ReLU, 4x4 tile, XCD-swizzled ---------------
// blockIdx.x (0..511): xcd = bid&7 -> b = xcd>>1; i = bid>>3 -> y = i*2+(xcd&1)
__global__ __launch_bounds__(128, 3) void k_final(const bf16* __restrict__ cat_p,
                                                  const bf16* __restrict__ w2_t,
                                                  const float* __restrict__ cb,
                                                  const float* __restrict__ gamma,
                                                  const float* __restrict__ beta,
                                                  const float* __restrict__ mean,
                                                  const float* __restrict__ var,
                                                  float* __restrict__ out) {
  int bid = blockIdx.x;
  int xcd = bid & 7;
  int b = xcd >> 1;
  int y = ((bid >> 3) << 1) | (xcd & 1);
  int lane = threadIdx.x & 63;
  int wave = threadIdx.x >> 6;   // 0..1
  int lanelo = lane & 15;
  int quad = lane >> 4;
  int xw = wave * 64;

  const bf16* cbase = cat_p + (size_t)b * CAT_PLANE + (size_t)(xw + lanelo) * 256 + quad * 8;
  const bf16* wbase = w2_t + lanelo * 256 + quad * 8;

  // step s = tap*8 + kci  (tap 0..8, kci 0..7)
  auto wptr = [&](int s) {
    int tap = s >> 3, kc = (s & 7) * 32;
    return wbase + (size_t)tap * 16384 + kc;
  };
  auto bptr = [&](int s) {
    int tap = s >> 3, kc = (s & 7) * 32;
    int ky = tap / 3, kx = tap % 3;
    return cbase + (size_t)(y + ky) * CAT_ROW + (size_t)kx * 256 + kc;
  };

  const int NSTEP = 72;
  bf16x8 a[2][4], bv[2][4];
  {
    const bf16* wp = wptr(0);
    const bf16* bp = bptr(0);
#pragma unroll
    for (int mt = 0; mt < 4; ++mt) a[0][mt] = *(const bf16x8*)(wp + mt * 4096);
#pragma unroll
    for (int nt = 0; nt < 4; ++nt) bv[0][nt] = *(const bf16x8*)(bp + nt * 4096);
  }

  f32x4 acc[4][4] = {};
#pragma unroll
  for (int s = 0; s < NSTEP; ++s) {
    int cur = s & 1, nxt = cur ^ 1;
    if (s + 1 < NSTEP) {
      const bf16* wp = wptr(s + 1);
      const bf16* bp = bptr(s + 1);
#pragma unroll
      for (int mt = 0; mt < 4; ++mt) a[nxt][mt] = *(const bf16x8*)(wp + mt * 4096);
#pragma unroll
      for (int nt = 0; nt < 4; ++nt) bv[nxt][nt] = *(const bf16x8*)(bp + nt * 4096);
    }
#pragma unroll
    for (int mt = 0; mt < 4; ++mt)
#pragma unroll
      for (int nt = 0; nt < 4; ++nt)
        acc[mt][nt] = __builtin_amdgcn_mfma_f32_16x16x32_bf16(a[cur][mt], bv[cur][nt], acc[mt][nt], 0, 0, 0);
  }

#pragma unroll
  for (int mt = 0; mt < 4; ++mt) {
#pragma unroll
    for (int nt = 0; nt < 4; ++nt) {
      int px = xw + nt * 16 + lanelo;
#pragma unroll
      for (int r = 0; r < 4; ++r) {
        int oc = mt * 16 + quad * 4 + r;
        float inv = gamma[oc] * rsqrtf(var[oc] + 1e-5f);
        float v = (acc[mt][nt][r] + cb[oc]) * inv + beta[oc] - mean[oc] * inv;
        out[((size_t)(b * 64 + oc)) * HW + y * 128 + px] = fmaxf(v, 0.0f);
      }
    }
  }
}

extern "C" void kernel_launch(void* const* d_in, const int* in_sizes, int n_in,
                              void* d_out, int out_size, void* d_ws, size_t ws_size,
                              hipStream_t stream) {
  const float* x     = (const float*)d_in[0];
  const float* kern  = (const float*)d_in[1];
  const float* mw    = (const float*)d_in[2];
  const float* mb    = (const float*)d_in[3];
  const float* w2    = (const float*)d_in[4];
  const float* cb    = (const float*)d_in[5];
  const float* gamma = (const float*)d_in[6];
  const float* beta  = (const float*)d_in[7];
  const float* mean  = (const float*)d_in[8];
  const float* var   = (const float*)d_in[9];

  float* out   = (float*)d_out;
  float* masks = out + OUT_ELEMS;

  char* ws = (char*)d_ws;
  // xm_p : 12 planes * 1,290,496 el * 2B = 30,971,904 B
  // cat_p:  4 planes * 4,326,400 el * 2B = 34,611,200 B  (ends 65,583,104)
  bf16* xm_p   = (bf16*)(ws);
  bf16* cat_p  = (bf16*)(ws + 30971904);
  bf16* kern_t = (bf16*)(ws + 65583104);   // 884,736 B
  bf16* w2_t   = (bf16*)(ws + 66467840);   // 294,912 B -> total 66,762,752 B
  // mask partials alias cat_p region (consumed by k_mask2 before k_branch/k_cat_halo write)
  float* part  = (float*)(ws + 30971904);  // 6,291,456 B < cat_p size

  k_wt<<<2304, 256, 0, stream>>>(kern, w2, kern_t, w2_t);
  k_mask1<<<dim3(128, 4, 8), 128, 0, stream>>>(x, mw, part);
  k_mask2<<<dim3(128, 4), 128, 0, stream>>>(part, mb, masks);
  k_xmt<<<dim3(142, 3, 4), 256, 0, stream>>>(x, masks, xm_p);
  k_cat_halo<<<258, 256, 0, stream>>>(cat_p);
  k_branch<<<2048, 128, 0, stream>>>(xm_p, kern_t, cat_p);
  k_final<<<512, 128, 0, stream>>>(cat_p, w2_t, cb, gamma, beta, mean, var, out);
}

// Round 6
// 318.876 us; speedup vs baseline: 1.3769x; 1.3769x over previous
//
#include <hip/hip_runtime.h>
#include <math.h>

typedef __bf16 bf16;
typedef __bf16 bf16x8 __attribute__((ext_vector_type(8)));
typedef __bf16 bf16x4 __attribute__((ext_vector_type(4)));
typedef float  f32x4  __attribute__((ext_vector_type(4)));

#define HW        16384      // 128*128
#define OUT_ELEMS 4194304    // 4*64*128*128

// padded xm: [b][m][yp=142][xp=142][c=64], pixel (y,x) at (y+7, x+7)
#define XM_ROW    (142 * 64)
#define XM_PLANE  (142 * XM_ROW)          // 1,290,496 el
// padded cat: [b][yp=130][xp=130][ch=256], pixel (y,x) at (y+1, x+1)
#define CAT_ROW   (130 * 256)
#define CAT_PLANE (130 * CAT_ROW)         // 4,326,400 el

// LDS pixel stride (elements): 64 payload + 8 pad -> 144 B, kills bank conflicts
#define LPX 72

// ---------------- weight transforms (fp32 -> bf16, tap-major, c innermost) ----
__global__ void k_wt(const float* __restrict__ kern, const float* __restrict__ w2,
                     bf16* __restrict__ kern_t, bf16* __restrict__ w2_t) {
  int i = blockIdx.x * 256 + threadIdx.x;
  const int N1 = 4 * 3 * 9 * 64 * 64;   // 442368
  if (i < N1) {
    int c = i & 63, o = (i >> 6) & 63, tap = (i >> 12) % 9, bm = i / 36864;
    kern_t[i] = (bf16)kern[(((bm * 64 + o) * 64 + c) * 9) + tap];
  } else {
    int j = i - N1;
    if (j < 64 * 256 * 9) {
      int ch = j & 255, oc = (j >> 8) & 63, tap = j >> 14;
      w2_t[j] = (bf16)w2[(oc * 256 + ch) * 9 + tap];
    }
  }
}

// -------- mask conv stage 1: partial logits over 8-channel groups ------------
__global__ void k_mask1(const float* __restrict__ x, const float* __restrict__ mw,
                        float* __restrict__ part) {
  int y = blockIdx.x, b = blockIdx.y, cg = blockIdx.z;
  int tx = threadIdx.x;      // 0..127
  float a0 = 0.f, a1 = 0.f, a2 = 0.f;
#pragma unroll
  for (int ci = 0; ci < 8; ++ci) {
    int c = cg * 8 + ci;
    const float* xp = x + ((size_t)(b * 64 + c)) * HW;
    const float* w0 = mw + (0 * 64 + c) * 9;
    const float* w1 = mw + (1 * 64 + c) * 9;
    const float* w2 = mw + (2 * 64 + c) * 9;
#pragma unroll
    for (int ky = 0; ky < 3; ++ky) {
      int yy = y + ky - 1;
      if ((unsigned)yy >= 128u) continue;
#pragma unroll
      for (int kx = 0; kx < 3; ++kx) {
        int xx = tx + kx - 1;
        if ((unsigned)xx >= 128u) continue;
        float xv = xp[yy * 128 + xx];
        a0 += xv * w0[ky * 3 + kx];
        a1 += xv * w1[ky * 3 + kx];
        a2 += xv * w2[ky * 3 + kx];
      }
    }
  }
  size_t base = (size_t)((b * 8 + cg) * 3) * HW + y * 128 + tx;
  part[base]          = a0;
  part[base + HW]     = a1;
  part[base + 2 * HW] = a2;
}

// -------- mask conv stage 2: reduce groups + bias + softmax ------------------
__global__ void k_mask2(const float* __restrict__ part, const float* __restrict__ mb,
                        float* __restrict__ masks) {
  int y = blockIdx.x, b = blockIdx.y;
  int tx = threadIdx.x;
  float a0 = mb[0], a1 = mb[1], a2 = mb[2];
  int off = y * 128 + tx;
#pragma unroll
  for (int cg = 0; cg < 8; ++cg) {
    size_t base = (size_t)((b * 8 + cg) * 3) * HW + off;
    a0 += part[base];
    a1 += part[base + HW];
    a2 += part[base + 2 * HW];
  }
  float mx = fmaxf(a0, fmaxf(a1, a2));
  float e0 = __expf(a0 - mx), e1 = __expf(a1 - mx), e2 = __expf(a2 - mx);
  float inv = 1.0f / (e0 + e1 + e2);
  size_t base = ((size_t)b * 3) * HW + off;
  masks[base]          = e0 * inv;
  masks[base + HW]     = e1 * inv;
  masks[base + 2 * HW] = e2 * inv;
}

// -------- xm = x * mask, NCHW fp32 -> padded NHWC(c=64) bf16, incl. halo -----
__global__ void k_xmt(const float* __restrict__ x, const float* __restrict__ masks,
                      bf16* __restrict__ xm_p) {
  int yp = blockIdx.x;  // 0..141 padded row
  int m = blockIdx.y, b = blockIdx.z;
  int t = threadIdx.x;  // 256
  bf16* prow = xm_p + (size_t)(b * 3 + m) * XM_PLANE + (size_t)yp * XM_ROW;
  bf16x8 z = {};
  if (yp < 7 || yp >= 135) {          // full halo row: 142*64/8 = 1136 chunks
#pragma unroll
    for (int i = 0; i < 5; ++i) {
      int u = i * 256 + t;
      if (u < 1136) ((bf16x8*)prow)[u] = z;
    }
    return;
  }
  // side halo: 7 px * 64c = 448 el = 56 chunks each side
  if (t < 56) ((bf16x8*)prow)[t] = z;
  else if (t < 112) ((bf16x8*)(prow + 135 * 64))[t - 56] = z;

  int y = yp - 7;
  __shared__ float tile[64 * 130];
#pragma unroll
  for (int i = 0; i < 32; ++i) {
    int u = i * 256 + t;           // 0..8191
    int c = u >> 7, xx = u & 127;
    tile[c * 130 + xx] = x[((size_t)(b * 64 + c)) * HW + y * 128 + xx];
  }
  __syncthreads();
  const float* mrow = masks + ((size_t)(b * 3 + m)) * HW + y * 128;
  bf16* orow = prow + 7 * 64;
#pragma unroll
  for (int i = 0; i < 32; ++i) {
    int u = i * 256 + t;
    int c = u & 63, xx = u >> 6;
    orow[xx * 64 + c] = (bf16)(tile[c * 130 + xx] * mrow[xx]);
  }
}

// ---------------- zero the halo of cat_p (516 px * 256 ch per plane) ---------
__global__ void k_cat_halo(bf16* __restrict__ cat_p) {
  int id = blockIdx.x * 256 + threadIdx.x;
  if (id >= 4 * 16512) return;
  int plane = id / 16512, j = id % 16512;
  bf16* base = cat_p + (size_t)plane * CAT_PLANE;
  bf16x8 zv = {};
  if (j < 8320) {                         // rows 0 and 129, full 130 px
    int row = (j / 4160) * 129;
    int off = (j % 4160) * 8;
    *(bf16x8*)(base + (size_t)row * CAT_ROW + off) = zv;
  } else {                                // rows 1..128, cols 0 and 129
    int k = j - 8320;
    int row = 1 + (k >> 6);
    int idx = k & 63;
    int col = (idx >> 5) * 129;
    int ch8 = (idx & 31) * 8;
    *(bf16x8*)(base + (size_t)row * CAT_ROW + col * 256 + ch8) = zv;
  }
}

// ------- branch convs: LDS-staged implicit GEMM ------------------------------
// block = 256 thr (4 waves), tile = 64 o x 128 px x 2 rows (y, y+1).
// 9 phases (m,ky): stage xm rows r=y+d(ky-1), r+1 (contiguous 36,352 B) into
// bank-padded LDS; A (24 frags) register-hoisted per phase; B via ds_read_b128.
__global__ __launch_bounds__(256, 2) void k_branch(const bf16* __restrict__ xm_p,
                                                   const bf16* __restrict__ kern_t,
                                                   bf16* __restrict__ cat_p) {
  __shared__ bf16 sb[2 * 142 * LPX];   // 40,896 B
  int bid = blockIdx.x;
  int xcd = bid & 7;
  int i   = bid >> 3;          // 0..127
  int b   = xcd >> 1;
  int di  = ((xcd & 1) << 1) | (i & 1);
  int y   = (i >> 1) * 2;      // 0,2,..,126
  int d   = 1 + 2 * di;        // 1,3,5,7
  int t    = threadIdx.x;
  int lane = t & 63;
  int wave = t >> 6;           // 0..3
  int wr   = wave >> 1;        // out-row 0/1
  int wc   = wave & 1;         // px half 0/1
  int lanelo = lane & 15;
  int quad = lane >> 4;

  const bf16* plane0 = xm_p + (size_t)(b * 3) * XM_PLANE;
  const bf16* wb0    = kern_t + (size_t)(b * 3 * 9) * 4096 + (lanelo * 64 + quad * 8);

  // prologue: issue staging loads for phase 0
  bf16x8 sreg[9];
  {
    const bf16* s0 = plane0 + (size_t)(y + 7 - d) * XM_ROW;   // m=0, ky=0
#pragma unroll
    for (int r = 0; r < 9; ++r) {
      int u = r * 256 + t;
      if (u < 2272) sreg[r] = *(const bf16x8*)(s0 + u * 8);
    }
  }

  f32x4 acc[4][4] = {};

#pragma unroll
  for (int p = 0; p < 9; ++p) {
    int m = p / 3, ky = p % 3;
    // A-frag loads for this phase (24 x 16B; 24 KB region, L1-resident)
    bf16x8 areg[3][2][4];
    const bf16* wtap = wb0 + (size_t)(m * 9 + ky * 3) * 4096;
#pragma unroll
    for (int kx = 0; kx < 3; ++kx)
#pragma unroll
      for (int kci = 0; kci < 2; ++kci)
#pragma unroll
        for (int mt = 0; mt < 4; ++mt)
          areg[kx][kci][mt] = *(const bf16x8*)(wtap + kx * 4096 + mt * 1024 + kci * 32);

    __syncthreads();   // previous phase's LDS reads done
    // write staged rows (swizzle-free: padded px stride)
#pragma unroll
    for (int r = 0; r < 9; ++r) {
      int u = r * 256 + t;
      if (u < 2272) {
        int pxL = u >> 3, c8 = u & 7;
        *(bf16x8*)(sb + pxL * LPX + c8 * 8) = sreg[r];
      }
    }
    // issue staging loads for next phase
    if (p < 8) {
      int pn = p + 1;
      int mn = pn / 3, kyn = pn % 3;
      const bf16* sn = plane0 + (size_t)mn * XM_PLANE
                     + (size_t)(y + 7 + d * (kyn - 1)) * XM_ROW;
#pragma unroll
      for (int r = 0; r < 9; ++r) {
        int u = r * 256 + t;
        if (u < 2272) sreg[r] = *(const bf16x8*)(sn + u * 8);
      }
    }
    __syncthreads();   // staged data visible
    // compute: 3 kx x 2 kc halves x 16 MFMA
#pragma unroll
    for (int kx = 0; kx < 3; ++kx) {
      int p0 = 7 + d * (kx - 1) + wc * 64 + lanelo;
      int base = (wr * 142 + p0) * LPX + quad * 8;
#pragma unroll
      for (int kci = 0; kci < 2; ++kci) {
        bf16x8 bv[4];
#pragma unroll
        for (int nt = 0; nt < 4; ++nt)
          bv[nt] = *(const bf16x8*)(sb + base + nt * (16 * LPX) + kci * 32);
#pragma unroll
        for (int mt = 0; mt < 4; ++mt)
#pragma unroll
          for (int nt = 0; nt < 4; ++nt)
            acc[mt][nt] = __builtin_amdgcn_mfma_f32_16x16x32_bf16(areg[kx][kci][mt], bv[nt], acc[mt][nt], 0, 0, 0);
      }
    }
  }

  // epilogue: cat_p[b][y+wr+1][px+1][di*64+o] bf16
  bf16* cp = cat_p + (size_t)b * CAT_PLANE + (size_t)(y + wr + 1) * CAT_ROW + di * 64;
#pragma unroll
  for (int mt = 0; mt < 4; ++mt) {
#pragma unroll
    for (int nt = 0; nt < 4; ++nt) {
      int px = wc * 64 + nt * 16 + lanelo;
      bf16x4 v;
#pragma unroll
      for (int r = 0; r < 4; ++r) v[r] = (bf16)acc[mt][nt][r];
      *(bf16x4*)(cp + (size_t)(px + 1) * 256 + (mt * 16 + quad * 4)) = v;
    }
  }
}

// ------- final conv + bias + BN + ReLU: LDS-staged ---------------------------
// block = 256 thr (4 waves), tile = 64 o x 128 px x 2 rows.
// 12 phases (ky, cq): stage 2 cat rows' 64-ch slice (33,280 B) into LDS.
__global__ __launch_bounds__(256, 1) void k_final(const bf16* __restrict__ cat_p,
                                                  const bf16* __restrict__ w2_t,
                                                  const float* __restrict__ cb,
                                                  const float* __restrict__ gamma,
                                                  const float* __restrict__ beta,
                                                  const float* __restrict__ mean,
                                                  const float* __restrict__ var,
                                                  float* __restrict__ out) {
  __shared__ bf16 sb[2 * 130 * LPX];   // 37,440 B
  int bid = blockIdx.x;                 // 0..255
  int xcd = bid & 7;
  int b   = xcd >> 1;
  int y   = (((bid >> 3) << 1) | (xcd & 1)) * 2;   // 0,2,..,126
  int t    = threadIdx.x;
  int lane = t & 63;
  int wave = t >> 6;
  int wr   = wave >> 1;
  int wc   = wave & 1;
  int lanelo = lane & 15;
  int quad = lane >> 4;

  const bf16* cbase = cat_p + (size_t)b * CAT_PLANE;
  const bf16* wbase = w2_t + (lanelo * 256 + quad * 8);

  // prologue: staging loads for phase 0 (ky=0, cq=0): rows y, y+1, ch 0..63
  bf16x8 sreg[2][5];
#pragma unroll
  for (int rr = 0; rr < 2; ++rr) {
    const bf16* s0 = cbase + (size_t)(y + rr) * CAT_ROW;
#pragma unroll
    for (int r = 0; r < 5; ++r) {
      int u = r * 256 + t;
      if (u < 1040) sreg[rr][r] = *(const bf16x8*)(s0 + (u >> 3) * 256 + (u & 7) * 8);
    }
  }

  f32x4 acc[4][4] = {};

#pragma unroll
  for (int p = 0; p < 12; ++p) {
    int ky = p >> 2, cq = p & 3;
    // A frags: 3 kx x 2 kc x 4 mt
    bf16x8 areg[3][2][4];
#pragma unroll
    for (int kx = 0; kx < 3; ++kx)
#pragma unroll
      for (int kci = 0; kci < 2; ++kci)
#pragma unroll
        for (int mt = 0; mt < 4; ++mt)
          areg[kx][kci][mt] = *(const bf16x8*)(wbase + (size_t)((ky * 3 + kx) * 64 + mt * 16) * 256
                                               + cq * 64 + kci * 32);

    __syncthreads();
#pragma unroll
    for (int rr = 0; rr < 2; ++rr)
#pragma unroll
      for (int r = 0; r < 5; ++r) {
        int u = r * 256 + t;
        if (u < 1040) {
          int px = u >> 3, c8 = u & 7;
          *(bf16x8*)(sb + (rr * 130 + px) * LPX + c8 * 8) = sreg[rr][r];
        }
      }
    if (p < 11) {
      int pn = p + 1;
      int kyn = pn >> 2, cqn = pn & 3;
#pragma unroll
      for (int rr = 0; rr < 2; ++rr) {
        const bf16* sn = cbase + (size_t)(y + kyn + rr) * CAT_ROW + cqn * 64;
#pragma unroll
        for (int r = 0; r < 5; ++r) {
          int u = r * 256 + t;
          if (u < 1040) sreg[rr][r] = *(const bf16x8*)(sn + (u >> 3) * 256 + (u & 7) * 8);
        }
      }
    }
    __syncthreads();
#pragma unroll
    for (int kx = 0; kx < 3; ++kx) {
      int p0 = wc * 64 + lanelo + kx;
      int base = (wr * 130 + p0) * LPX + quad * 8;
#pragma unroll
      for (int kci = 0; kci < 2; ++kci) {
        bf16x8 bv[4];
#pragma unroll
        for (int nt = 0; nt < 4; ++nt)
          bv[nt] = *(const bf16x8*)(sb + base + nt * (16 * LPX) + kci * 32);
#pragma unroll
        for (int mt = 0; mt < 4; ++mt)
#pragma unroll
          for (int nt = 0; nt < 4; ++nt)
            acc[mt][nt] = __builtin_amdgcn_mfma_f32_16x16x32_bf16(areg[kx][kci][mt], bv[nt], acc[mt][nt], 0, 0, 0);
      }
    }
  }

#pragma unroll
  for (int mt = 0; mt < 4; ++mt) {
#pragma unroll
    for (int nt = 0; nt < 4; ++nt) {
      int px = wc * 64 + nt * 16 + lanelo;
#pragma unroll
      for (int r = 0; r < 4; ++r) {
        int oc = mt * 16 + quad * 4 + r;
        float inv = gamma[oc] * rsqrtf(var[oc] + 1e-5f);
        float v = (acc[mt][nt][r] + cb[oc]) * inv + beta[oc] - mean[oc] * inv;
        out[((size_t)(b * 64 + oc)) * HW + (y + wr) * 128 + px] = fmaxf(v, 0.0f);
      }
    }
  }
}

extern "C" void kernel_launch(void* const* d_in, const int* in_sizes, int n_in,
                              void* d_out, int out_size, void* d_ws, size_t ws_size,
                              hipStream_t stream) {
  const float* x     = (const float*)d_in[0];
  const float* kern  = (const float*)d_in[1];
  const float* mw    = (const float*)d_in[2];
  const float* mb    = (const float*)d_in[3];
  const float* w2    = (const float*)d_in[4];
  const float* cb    = (const float*)d_in[5];
  const float* gamma = (const float*)d_in[6];
  const float* beta  = (const float*)d_in[7];
  const float* mean  = (const float*)d_in[8];
  const float* var   = (const float*)d_in[9];

  float* out   = (float*)d_out;
  float* masks = out + OUT_ELEMS;

  char* ws = (char*)d_ws;
  bf16* xm_p   = (bf16*)(ws);              // 30,971,904 B
  bf16* cat_p  = (bf16*)(ws + 30971904);   // 34,611,200 B (ends 65,583,104)
  bf16* kern_t = (bf16*)(ws + 65583104);   // 884,736 B
  bf16* w2_t   = (bf16*)(ws + 66467840);   // 294,912 B -> total 66,762,752 B
  // mask partials alias cat_p region (consumed before k_branch/k_cat_halo write)
  float* part  = (float*)(ws + 30971904);  // 6,291,456 B < cat_p size

  k_wt<<<2304, 256, 0, stream>>>(kern, w2, kern_t, w2_t);
  k_mask1<<<dim3(128, 4, 8), 128, 0, stream>>>(x, mw, part);
  k_mask2<<<dim3(128, 4), 128, 0, stream>>>(part, mb, masks);
  k_xmt<<<dim3(142, 3, 4), 256, 0, stream>>>(x, masks, xm_p);
  k_cat_halo<<<258, 256, 0, stream>>>(cat_p);
  k_branch<<<1024, 256, 0, stream>>>(xm_p, kern_t, cat_p);
  k_final<<<256, 256, 0, stream>>>(cat_p, w2_t, cb, gamma, beta, mean, var, out);
}